// Round 2
// baseline (1208.432 us; speedup 1.0000x reference)
//
#include <hip/hip_runtime.h>
#include <math.h>

#define NN 16000
#define EE 256000
#define GG 64
#define KK 10
#define CC 32
#define NBB 8
#define MHH 16
#define NPP 4
#define NEE 3
#define NDD 6
#define SHH 9
#define RHH 64
#define SHCC (SHH*CC)   // 288

__device__ __forceinline__ float siluf(float x){ return x / (1.0f + __expf(-x)); }
__device__ __forceinline__ float bcastf(float v, int l){
  return __int_as_float(__builtin_amdgcn_readlane(__float_as_int(v), l));
}

// ---------------- init: kidx, feats[:,0,:] = W_embed[k], e0 per graph ----------------
__global__ __launch_bounds__(256) void init_kernel(
    const float* __restrict__ attrs, const float* __restrict__ E0v,
    const float* __restrict__ Wemb, const int* __restrict__ batch,
    int* __restrict__ kidx, float* __restrict__ feats, float* __restrict__ e0g)
{
  int t = blockIdx.x*blockDim.x + threadIdx.x;
  if (t >= NN*CC) return;
  int n = t >> 5, d = t & 31;
  const float* a = attrs + n*KK;
  int k = 0; float best = a[0];
  #pragma unroll
  for (int j=1;j<KK;j++){ float v=a[j]; if (v>best){best=v;k=j;} }
  float* f = feats + n*SHCC;
  f[d] = Wemb[k*CC+d];
  #pragma unroll
  for (int s=1;s<SHH;s++) f[s*CC+d] = 0.0f;
  if (d==0){ kidx[n]=k; atomicAdd(&e0g[batch[n]], E0v[k]); }
}

// ---------------- up = feats[:,0,:] @ W_up[l], scaled by 1/AVG_NBR ----------------
__global__ __launch_bounds__(256) void up_kernel(
    const float* __restrict__ feats, const float* __restrict__ Wup,
    float* __restrict__ up)
{
  int t = blockIdx.x*blockDim.x + threadIdx.x;
  if (t >= NN*CC) return;
  int n = t >> 5, d = t & 31;
  const float* f = feats + n*SHCC;
  float acc = 0.0f;
  #pragma unroll
  for (int c=0;c<CC;c++) acc += f[c]*Wup[c*CC+d];
  up[t] = acc * 0.0625f;   // fold the /AVG_NBR of the segment mean here
}

// ---------------- fused edge kernel: geometry + radial MLP + msg + scatter ----------------
// one wave processes 4 edges at a time; weights staged in LDS (92 KB)
__global__ __launch_bounds__(1024) void edge_kernel(
    const float* __restrict__ pos, const float* __restrict__ shifts,
    const float* __restrict__ Wr1, const float* __restrict__ Wr2,
    const float* __restrict__ Wr3, const float* __restrict__ up,
    const int* __restrict__ ei, float* __restrict__ agg)
{
  __shared__ float sW1[NBB*RHH];   // 2 KB
  __shared__ float sW2[RHH*RHH];   // 16 KB
  __shared__ float sW3[RHH*SHCC];  // 73.7 KB
  for (int i=threadIdx.x;i<NBB*RHH;i+=1024)  sW1[i]=Wr1[i];
  for (int i=threadIdx.x;i<RHH*RHH;i+=1024)  sW2[i]=Wr2[i];
  for (int i=threadIdx.x;i<RHH*SHCC;i+=1024) sW3[i]=Wr3[i];
  __syncthreads();
  const int lane = threadIdx.x & 63;
  const int hh = lane >> 5;      // which half-wave
  const int cl = lane & 31;      // channel
  const int wid = blockIdx.x*(1024>>6) + (threadIdx.x>>6);
  const int nw = gridDim.x*(1024>>6);

  for (int eb = wid; eb < EE/4; eb += nw) {
    int srcv[4], dstv[4];
    float h1[4];
    float sA[4], sB[4], sC[4], sD[4], sE[4];
    #pragma unroll
    for (int q=0;q<4;q++){
      const int e = eb*4+q;
      const int src = ei[e], dst = ei[EE+e];
      srcv[q]=src; dstv[q]=dst;
      float x = pos[src*3+0]-pos[dst*3+0]+shifts[e*3+0];
      float y = pos[src*3+1]-pos[dst*3+1]+shifts[e*3+1];
      float z = pos[src*3+2]-pos[dst*3+2]+shifts[e*3+2];
      float r = sqrtf(x*x+y*y+z*z+1e-12f);
      float ir = 1.0f/r;
      x*=ir; y*=ir; z*=ir;
      const float S3=1.7320508075688772f, S5h=1.1180339887498949f;
      const float S15=3.872983346207417f, S15h=1.9364916731037085f;
      float g1=S3*x, g2=S3*y, g3=S3*z;
      float g4=S15*x*y, g5=S15*y*z, g6=S5h*(3.0f*z*z-1.0f), g7=S15*x*z, g8=S15h*(x*x-y*y);
      // sh index = 2t + hh for output block t; select per-lane constants (no dyn-indexed array)
      sA[q] = hh ? g1 : 1.0f;
      sB[q] = hh ? g3 : g2;
      sC[q] = hh ? g5 : g4;
      sD[q] = hh ? g7 : g6;
      sE[q] = g8;
      float u = r*0.2f;
      float u2=u*u, u3=u2*u, u6=u3*u3;
      float env = 1.0f - 28.0f*u6 + 48.0f*u6*u - 21.0f*u6*u2;
      env = (u<1.0f)? env : 0.0f;
      env *= ir * 0.6324555320336759f;   // sqrt(2/R_MAX)/r
      float sb, cb;
      __sincosf(3.14159265358979323846f*u, &sb, &cb);
      float twoc = 2.0f*cb;
      float sprev = 0.0f, scur = sb;     // sin(n*pi*u) by recurrence
      float acc = 0.0f;
      #pragma unroll
      for (int j=0;j<NBB;j++){
        acc += (scur*env)*sW1[j*RHH+lane];
        float snext = twoc*scur - sprev;
        sprev = scur; scur = snext;
      }
      h1[q] = siluf(acc);
    }
    // h2 = silu(h1 @ W2): h1 lives one value per lane (RH==64==wave)
    float a2[4] = {0.f,0.f,0.f,0.f};
    #pragma unroll 4
    for (int j=0;j<RHH;j++){
      float w = sW2[j*RHH+lane];
      a2[0] += bcastf(h1[0],j)*w;
      a2[1] += bcastf(h1[1],j)*w;
      a2[2] += bcastf(h1[2],j)*w;
      a2[3] += bcastf(h1[3],j)*w;
    }
    float h2[4];
    #pragma unroll
    for (int q=0;q<4;q++) h2[q]=siluf(a2[q]);

    // Rw3 = h2 @ W3 (288 outputs: lane + 64t, plus 256+lane for lane<32)
    float o0[4]={0,0,0,0}, o1[4]={0,0,0,0}, o2[4]={0,0,0,0}, o3[4]={0,0,0,0}, o4[4]={0,0,0,0};
    #pragma unroll 2
    for (int j=0;j<RHH;j++){
      const float* w = &sW3[j*SHCC];
      float w0=w[lane], w1=w[RHH+lane], w2=w[2*RHH+lane], w3=w[3*RHH+lane], w4=w[4*RHH+cl];
      #pragma unroll
      for (int q=0;q<4;q++){
        float b = bcastf(h2[q],j);
        o0[q]+=b*w0; o1[q]+=b*w1; o2[q]+=b*w2; o3[q]+=b*w3; o4[q]+=b*w4;
      }
    }
    #pragma unroll
    for (int q=0;q<4;q++){
      float uc = up[srcv[q]*CC + cl];
      float* ag = agg + dstv[q]*SHCC;
      atomicAdd(ag + lane,          o0[q]*sA[q]*uc);
      atomicAdd(ag + RHH+lane,      o1[q]*sB[q]*uc);
      atomicAdd(ag + 2*RHH+lane,    o2[q]*sC[q]*uc);
      atomicAdd(ag + 3*RHH+lane,    o3[q]*sD[q]*uc);
      if (hh==0) atomicAdd(ag + 4*RHH+lane, o4[q]*sE[q]*uc);
    }
  }
}

// ---------------- node update + readouts; 8 nodes x 32 lanes per block ----------------
__global__ __launch_bounds__(256) void node_kernel(
    const float* __restrict__ feats, float* __restrict__ fout,
    const float* __restrict__ agg,
    const int* __restrict__ kidx, const int* __restrict__ batch,
    const float* __restrict__ Wsc, const float* __restrict__ Wprod,
    const float* __restrict__ WcL,
    const float* __restrict__ We1, const float* __restrict__ We2,
    const float* __restrict__ Wi1, const float* __restrict__ Wi2,
    const float* __restrict__ Wdp,
    float* __restrict__ eng, float* __restrict__ inv, float* __restrict__ dip)
{
  __shared__ float s0l[8][CC];
  __shared__ float sul[8][CC];
  __shared__ float vl[8][3][CC];
  __shared__ float hl[8][CC];
  const int t = threadIdx.x;
  const int nn = t >> 5;
  const int d = t & 31;
  const int n = blockIdx.x*8 + nn;
  const int k = kidx[n];
  const int b = batch[n];
  const float* fin = feats + n*SHCC;
  const float* ag = agg + n*SHCC;
  float nw[SHH];
  const int LV[SHH] = {0,1,1,1,2,2,2,2,2};
  #pragma unroll
  for (int s=0;s<SHH;s++){
    const int lv = LV[s];
    const float* wp  = Wprod + lv*CC*CC + d;
    const float* wsc = Wsc + (k*3+lv)*CC*CC + d;
    float acc = 0.0f;
    #pragma unroll
    for (int c=0;c<CC;c++)
      acc += ag[s*CC+c]*wp[c*CC] + fin[s*CC+c]*wsc[c*CC];
    nw[s] = acc;
  }
  s0l[nn][d] = nw[0];
  vl[nn][0][d] = nw[1]; vl[nn][1][d] = nw[2]; vl[nn][2][d] = nw[3];
  __syncthreads();
  float corr = 0.0f;
  {
    const float* wc0 = WcL + (0*KK+k)*CC*CC + d;
    const float* wc1 = WcL + (1*KK+k)*CC*CC + d;
    const float* wc2 = WcL + (2*KK+k)*CC*CC + d;
    #pragma unroll
    for (int c=0;c<CC;c++){
      float s0 = s0l[nn][c];
      float s2 = s0*s0;
      corr += s0*wc0[c*CC] + s2*wc1[c*CC] + s2*s0*wc2[c*CC];
    }
  }
  float su = nw[0] + corr;
  sul[nn][d] = su;
  float* fo = fout + n*SHCC;
  fo[d] = su;
  #pragma unroll
  for (int s=1;s<SHH;s++) fo[s*CC+d] = nw[s];
  __syncthreads();
  {
    const int m = d & 15;
    const float* W = (d < MHH) ? We1 : Wi1;
    float acc = 0.0f;
    #pragma unroll
    for (int c=0;c<CC;c++) acc += sul[nn][c]*W[c*MHH+m];
    hl[nn][d] = siluf(acc);
  }
  __syncthreads();
  if (d < NEE){
    float acc=0.0f;
    #pragma unroll
    for (int m=0;m<MHH;m++) acc += hl[nn][m]*We2[m*NEE+d];
    atomicAdd(&eng[b*NEE+d], acc);
  } else if (d < NEE+NPP){
    const int p = d-NEE;
    float acc=0.0f;
    #pragma unroll
    for (int m=0;m<MHH;m++) acc += hl[nn][MHH+m]*Wi2[m*NPP+p];
    atomicAdd(&inv[b*NPP+p], acc);
  } else if (d < 7+3*NDD){
    const int idx = d-7;
    const int v = idx/NDD;
    const int dd = idx - v*NDD;
    float acc=0.0f;
    #pragma unroll
    for (int c=0;c<CC;c++) acc += vl[nn][v][c]*Wdp[c*NDD+dd];
    atomicAdd(&dip[(b*3+v)*NDD+dd], acc);
  }
}

// ---------------- final decode + assembly ----------------
__global__ __launch_bounds__(64) void final_kernel(
    const float* __restrict__ eng, const float* __restrict__ inv,
    const float* __restrict__ dip, const float* __restrict__ e0g,
    const float* __restrict__ Wd1, const float* __restrict__ bd1,
    const float* __restrict__ Wd2, const float* __restrict__ bd2,
    float* __restrict__ out)
{
  const int g = threadIdx.x;
  if (g >= GG) return;
  float e0 = e0g[g];
  float iv0=inv[g*NPP+0], iv1=inv[g*NPP+1], iv2=inv[g*NPP+2], iv3=inv[g*NPP+3];
  float o0=bd2[0], o1=bd2[1], o2=bd2[2];
  for (int m=0;m<RHH;m++){
    float hm = bd1[m] + iv0*Wd1[0*RHH+m] + iv1*Wd1[1*RHH+m] + iv2*Wd1[2*RHH+m] + iv3*Wd1[3*RHH+m];
    hm = siluf(hm);
    o0 += hm*Wd2[m*NEE+0]; o1 += hm*Wd2[m*NEE+1]; o2 += hm*Wd2[m*NEE+2];
  }
  float* og = out + g*24;
  og[0]=o0+e0; og[1]=o1+e0; og[2]=o2+e0;
  og[3]=eng[g*NEE+0]+e0; og[4]=eng[g*NEE+1]+e0; og[5]=eng[g*NEE+2]+e0;
  for (int dd=0;dd<NDD;dd++)
    for (int v=0;v<3;v++)
      og[6+dd*3+v] = dip[(g*3+v)*NDD+dd];
}

extern "C" void kernel_launch(void* const* d_in, const int* in_sizes, int n_in,
                              void* d_out, int out_size, void* d_ws, size_t ws_size,
                              hipStream_t stream)
{
  const float* pos    = (const float*)d_in[0];
  const float* attrs  = (const float*)d_in[1];
  const float* shifts = (const float*)d_in[2];
  const float* E0v    = (const float*)d_in[3];
  const float* Wemb   = (const float*)d_in[4];
  const float* Wup    = (const float*)d_in[5];
  const float* Wr1    = (const float*)d_in[6];
  const float* Wr2    = (const float*)d_in[7];
  const float* Wr3    = (const float*)d_in[8];
  const float* Wsc    = (const float*)d_in[9];
  const float* Wprod  = (const float*)d_in[10];
  const float* Wc     = (const float*)d_in[11];
  const float* We1    = (const float*)d_in[12];
  const float* We2    = (const float*)d_in[13];
  const float* Wi1    = (const float*)d_in[14];
  const float* Wi2    = (const float*)d_in[15];
  const float* Wdp    = (const float*)d_in[16];
  const float* Wd1    = (const float*)d_in[17];
  const float* bd1    = (const float*)d_in[18];
  const float* Wd2    = (const float*)d_in[19];
  const float* bd2    = (const float*)d_in[20];
  const int*   ei     = (const int*)d_in[21];
  const int*   batch  = (const int*)d_in[22];
  float* out = (float*)d_out;

  float* feats = (float*)d_ws;                 // N*288
  float* agg   = feats + (size_t)NN*SHCC;      // N*288
  float* up    = agg   + (size_t)NN*SHCC;      // N*32
  float* accum = up    + (size_t)NN*CC;        // 1664 floats
  float* e0g = accum;          // 64
  float* eng = accum + 64;     // 64*3
  float* inv = accum + 256;    // 64*4
  float* dip = accum + 512;    // 64*18
  int*   kidx = (int*)(accum + 1664);          // N ints

  hipMemsetAsync(accum, 0, 1664*sizeof(float), stream);
  init_kernel<<<(NN*CC)/256, 256, 0, stream>>>(attrs, E0v, Wemb, batch, kidx, feats, e0g);

  for (int l=0; l<2; ++l){
    up_kernel<<<(NN*CC)/256, 256, 0, stream>>>(feats, Wup + l*CC*CC, up);
    hipMemsetAsync(agg, 0, (size_t)NN*SHCC*sizeof(float), stream);
    edge_kernel<<<256, 1024, 0, stream>>>(pos, shifts,
        Wr1 + l*NBB*RHH, Wr2 + l*RHH*RHH, Wr3 + l*RHH*SHCC,
        up, ei, agg);
    node_kernel<<<NN/8, 256, 0, stream>>>(feats, feats, agg, kidx, batch,
        Wsc + l*KK*3*CC*CC, Wprod + l*3*CC*CC, Wc + l*3*KK*CC*CC,
        We1 + l*CC*MHH, We2 + l*MHH*NEE, Wi1 + l*CC*MHH, Wi2 + l*MHH*NPP,
        Wdp + l*CC*NDD,
        eng, inv, dip);
  }
  final_kernel<<<1, 64, 0, stream>>>(eng, inv, dip, e0g, Wd1, bd1, Wd2, bd2, out);
}

// Round 4
// 970.723 us; speedup vs baseline: 1.2449x; 1.2449x over previous
//
#include <hip/hip_runtime.h>
#include <math.h>

#define NN 16000
#define EE 256000
#define GG 64
#define KK 10
#define CC 32
#define NBB 8
#define MHH 16
#define NPP 4
#define NEE 3
#define NDD 6
#define SHH 9
#define RHH 64
#define SHCC (SHH*CC)   // 288

typedef __attribute__((ext_vector_type(8))) short s8b;    // bf16 frag (4 VGPR)
typedef __attribute__((ext_vector_type(4))) float f32x4;  // acc frag

__device__ __forceinline__ float siluf(float x){ return x / (1.0f + __expf(-x)); }
__device__ __forceinline__ short bf16rne(float x){
  unsigned u = __float_as_uint(x);
  unsigned r = u + 0x7FFFu + ((u>>16)&1u);
  return (short)(r>>16);
}

// ---------------- init ----------------
__global__ __launch_bounds__(256) void init_kernel(
    const float* __restrict__ attrs, const float* __restrict__ E0v,
    const float* __restrict__ Wemb, const int* __restrict__ batch,
    int* __restrict__ kidx, float* __restrict__ feats, float* __restrict__ e0g)
{
  int t = blockIdx.x*blockDim.x + threadIdx.x;
  if (t >= NN*CC) return;
  int n = t >> 5, d = t & 31;
  const float* a = attrs + n*KK;
  int k = 0; float best = a[0];
  #pragma unroll
  for (int j=1;j<KK;j++){ float v=a[j]; if (v>best){best=v;k=j;} }
  float* f = feats + n*SHCC;
  f[d] = Wemb[k*CC+d];
  #pragma unroll
  for (int s=1;s<SHH;s++) f[s*CC+d] = 0.0f;
  if (d==0){ kidx[n]=k; atomicAdd(&e0g[batch[n]], E0v[k]); }
}

// ---------------- up ----------------
__global__ __launch_bounds__(256) void up_kernel(
    const float* __restrict__ feats, const float* __restrict__ Wup,
    float* __restrict__ up)
{
  int t = blockIdx.x*blockDim.x + threadIdx.x;
  if (t >= NN*CC) return;
  int n = t >> 5, d = t & 31;
  const float* f = feats + n*SHCC;
  float acc = 0.0f;
  #pragma unroll
  for (int c=0;c<CC;c++) acc += f[c]*Wup[c*CC+d];
  up[t] = acc * 0.0625f;
}

// ---------------- fused MFMA edge kernel ----------------
// 256 threads = 4 independent waves; each wave does 16 edges per iteration.
// Weights in LDS as bf16, XOR-swizzled against stride-128B bank conflicts.
__global__ __launch_bounds__(256, 2) void edge_kernel(
    const float* __restrict__ pos, const float* __restrict__ shifts,
    const float* __restrict__ Wr1, const float* __restrict__ Wr2,
    const float* __restrict__ Wr3, const float* __restrict__ up,
    const int* __restrict__ ei, float* __restrict__ agg)
{
  __shared__ alignas(16) short sW3T[SHCC*RHH];  // [o=288][k=64] bf16, swizzled: 36.9KB
  __shared__ alignas(16) short sW2T[RHH*RHH];   // [kk=64][k=64] bf16, swizzled: 8KB
  __shared__ alignas(16) float sW1T[RHH*NBB];   // [k=64][b=8] f32: 2KB
  __shared__ alignas(16) float ef_l[4][16*8];   // per-wave edge_feats
  __shared__ alignas(16) float sh_l[4][16*12];  // per-wave sph
  __shared__ alignas(16) float h2t[4][16*68];   // per-wave h2 transpose (17*16B rows)

  // ---- stage weights (bf16, swizzled) ----
  for (int i=threadIdx.x; i<RHH*SHCC; i+=256){
    int kk = i/SHCC, o = i - kk*SHCC;                  // read coalesced over o
    sW3T[(o*RHH + kk) ^ ((o&7)<<3)] = bf16rne(Wr3[i]);
  }
  for (int i=threadIdx.x; i<RHH*RHH; i+=256){
    int k = i>>6, kk = i&63;
    sW2T[(kk*RHH + k) ^ ((kk&7)<<3)] = bf16rne(Wr2[i]);
  }
  for (int i=threadIdx.x; i<NBB*RHH; i+=256){
    int b = i>>6, k = i&63;
    sW1T[k*NBB + b] = Wr1[i];
  }
  __syncthreads();

  const int lane = threadIdx.x & 63;
  const int el   = lane & 15;        // edge-in-tile for input frags
  const int r    = lane >> 4;        // 16-lane group
  const int wv   = threadIdx.x >> 6;
  float* efw = ef_l[wv];
  float* shw = sh_l[wv];
  float* h2w = h2t[wv];
  const int wid = blockIdx.x*4 + wv;
  const int nw  = gridDim.x*4;
  const f32x4 zf = {0.f,0.f,0.f,0.f};
  const float PI_ = 3.14159265358979323846f;

  for (int tile = wid; tile < EE/16; tile += nw) {
    const int e0 = tile*16;
    // ---- geometry: lane handles edge e0+el; group r computes bessels r, r+4 ----
    {
      const int e = e0 + el;
      const int src = ei[e], dst = ei[EE+e]; (void)dst;
      float x = pos[src*3+0]-pos[ei[EE+e]*3+0]+shifts[e*3+0];
      float y = pos[src*3+1]-pos[ei[EE+e]*3+1]+shifts[e*3+1];
      float z = pos[src*3+2]-pos[ei[EE+e]*3+2]+shifts[e*3+2];
      float rr = sqrtf(x*x+y*y+z*z+1e-12f);
      float ir = 1.0f/rr;
      x*=ir; y*=ir; z*=ir;
      const float S3=1.7320508075688772f, S5h=1.1180339887498949f;
      const float S15=3.872983346207417f, S15h=1.9364916731037085f;
      if (r==0){ shw[el*12+0]=1.0f;            shw[el*12+1]=S3*x;     shw[el*12+2]=S3*y; }
      else if (r==1){ shw[el*12+3]=S3*z;       shw[el*12+4]=S15*x*y;  shw[el*12+5]=S15*y*z; }
      else if (r==2){ shw[el*12+6]=S5h*(3.0f*z*z-1.0f); shw[el*12+7]=S15*x*z; shw[el*12+8]=S15h*(x*x-y*y); }
      float u = rr*0.2f;
      float u2=u*u, u3=u2*u, u6=u3*u3;
      float env = 1.0f - 28.0f*u6 + 48.0f*u6*u - 21.0f*u6*u2;
      env = (u<1.0f)? env : 0.0f;
      env *= ir * 0.6324555320336759f;
      float n1 = (float)(r+1), n2 = (float)(r+5);
      efw[el*8 + r]     = __sinf(n1*PI_*u)*env;
      efw[el*8 + r + 4] = __sinf(n2*PI_*u)*env;
    }
    // ---- h1 = silu(ef @ W1), computed directly in A-frag layout ----
    float h1v[16];
    {
      f32x4 efa = *(const f32x4*)&efw[el*8];
      f32x4 efb = *(const f32x4*)&efw[el*8+4];
      #pragma unroll
      for (int s=0;s<2;s++){
        #pragma unroll
        for (int j=0;j<8;j++){
          int kq = 32*s + 8*r + j;
          f32x4 wa = *(const f32x4*)&sW1T[kq*NBB];
          f32x4 wb = *(const f32x4*)&sW1T[kq*NBB+4];
          float acc = efa[0]*wa[0]+efa[1]*wa[1]+efa[2]*wa[2]+efa[3]*wa[3]
                    + efb[0]*wb[0]+efb[1]*wb[1]+efb[2]*wb[2]+efb[3]*wb[3];
          h1v[s*8+j] = siluf(acc);
        }
      }
    }
    s8b a1s0, a1s1;
    #pragma unroll
    for (int j=0;j<8;j++){ a1s0[j]=bf16rne(h1v[j]); a1s1[j]=bf16rne(h1v[8+j]); }

    // ---- h2 = silu(h1 @ W2) via MFMA ----
    f32x4 aw2[4];
    #pragma unroll
    for (int t=0;t<4;t++){
      int kk = 16*t + el;
      int sw = (kk&7)<<3;
      s8b b0 = *(const s8b*)&sW2T[(kk*RHH + 8*r     ) ^ sw];
      s8b b1 = *(const s8b*)&sW2T[(kk*RHH + 8*r + 32) ^ sw];
      f32x4 acc = __builtin_amdgcn_mfma_f32_16x16x32_bf16(a1s0, b0, zf, 0,0,0);
      aw2[t]    = __builtin_amdgcn_mfma_f32_16x16x32_bf16(a1s1, b1, acc, 0,0,0);
    }
    // D layout: row e = 4*r+reg, col kk = 16t+el  -> transpose via LDS
    #pragma unroll
    for (int t=0;t<4;t++){
      #pragma unroll
      for (int reg=0;reg<4;reg++){
        int e = 4*r + reg;
        h2w[e*68 + 16*t + el] = siluf(aw2[t][reg]);
      }
    }
    s8b a2s0, a2s1;
    {
      f32x4 p0 = *(const f32x4*)&h2w[el*68 + 8*r];
      f32x4 p1 = *(const f32x4*)&h2w[el*68 + 8*r + 4];
      f32x4 p2 = *(const f32x4*)&h2w[el*68 + 8*r + 32];
      f32x4 p3 = *(const f32x4*)&h2w[el*68 + 8*r + 36];
      #pragma unroll
      for (int j=0;j<4;j++){
        a2s0[j]=bf16rne(p0[j]); a2s0[4+j]=bf16rne(p1[j]);
        a2s1[j]=bf16rne(p2[j]); a2s1[4+j]=bf16rne(p3[j]);
      }
    }
    // ---- per-output-edge data (e = 4*r+reg) ----
    int srcE[4], dstE[4];
    float upv[4][2];
    #pragma unroll
    for (int reg=0;reg<4;reg++){
      int ee = e0 + 4*r + reg;
      srcE[reg] = ei[ee]; dstE[reg] = ei[EE+ee];
      upv[reg][0] = up[srcE[reg]*CC + el];
      upv[reg][1] = up[srcE[reg]*CC + 16 + el];
    }
    // ---- Rw = h2 @ W3 via MFMA, fused scale + scatter ----
    #pragma unroll
    for (int t=0;t<18;t++){
      int o = 16*t + el;
      int sw = (o&7)<<3;
      s8b b0 = *(const s8b*)&sW3T[(o*RHH + 8*r     ) ^ sw];
      s8b b1 = *(const s8b*)&sW3T[(o*RHH + 8*r + 32) ^ sw];
      f32x4 acc = __builtin_amdgcn_mfma_f32_16x16x32_bf16(a2s0, b0, zf, 0,0,0);
      acc       = __builtin_amdgcn_mfma_f32_16x16x32_bf16(a2s1, b1, acc, 0,0,0);
      const int sidx = t>>1, spar = t&1;
      #pragma unroll
      for (int reg=0;reg<4;reg++){
        int e = 4*r + reg;
        float v = acc[reg] * shw[e*12 + sidx] * upv[reg][spar];
        atomicAdd(agg + (size_t)dstE[reg]*SHCC + o, v);
      }
    }
  }
}

// ---------------- node update + readouts ----------------
__global__ __launch_bounds__(256) void node_kernel(
    const float* __restrict__ feats, float* __restrict__ fout,
    const float* __restrict__ agg,
    const int* __restrict__ kidx, const int* __restrict__ batch,
    const float* __restrict__ Wsc, const float* __restrict__ Wprod,
    const float* __restrict__ WcL,
    const float* __restrict__ We1, const float* __restrict__ We2,
    const float* __restrict__ Wi1, const float* __restrict__ Wi2,
    const float* __restrict__ Wdp,
    float* __restrict__ eng, float* __restrict__ inv, float* __restrict__ dip)
{
  __shared__ float s0l[8][CC];
  __shared__ float sul[8][CC];
  __shared__ float vl[8][3][CC];
  __shared__ float hl[8][CC];
  const int t = threadIdx.x;
  const int nn = t >> 5;
  const int d = t & 31;
  const int n = blockIdx.x*8 + nn;
  const int k = kidx[n];
  const int b = batch[n];
  const float* fin = feats + n*SHCC;
  const float* ag = agg + n*SHCC;
  float nw[SHH];
  const int LV[SHH] = {0,1,1,1,2,2,2,2,2};
  #pragma unroll
  for (int s=0;s<SHH;s++){
    const int lv = LV[s];
    const float* wp  = Wprod + lv*CC*CC + d;
    const float* wsc = Wsc + (k*3+lv)*CC*CC + d;
    float acc = 0.0f;
    #pragma unroll
    for (int c=0;c<CC;c++)
      acc += ag[s*CC+c]*wp[c*CC] + fin[s*CC+c]*wsc[c*CC];
    nw[s] = acc;
  }
  s0l[nn][d] = nw[0];
  vl[nn][0][d] = nw[1]; vl[nn][1][d] = nw[2]; vl[nn][2][d] = nw[3];
  __syncthreads();
  float corr = 0.0f;
  {
    const float* wc0 = WcL + (0*KK+k)*CC*CC + d;
    const float* wc1 = WcL + (1*KK+k)*CC*CC + d;
    const float* wc2 = WcL + (2*KK+k)*CC*CC + d;
    #pragma unroll
    for (int c=0;c<CC;c++){
      float s0 = s0l[nn][c];
      float s2 = s0*s0;
      corr += s0*wc0[c*CC] + s2*wc1[c*CC] + s2*s0*wc2[c*CC];
    }
  }
  float su = nw[0] + corr;
  sul[nn][d] = su;
  float* fo = fout + n*SHCC;
  fo[d] = su;
  #pragma unroll
  for (int s=1;s<SHH;s++) fo[s*CC+d] = nw[s];
  __syncthreads();
  {
    const int m = d & 15;
    const float* W = (d < MHH) ? We1 : Wi1;
    float acc = 0.0f;
    #pragma unroll
    for (int c=0;c<CC;c++) acc += sul[nn][c]*W[c*MHH+m];
    hl[nn][d] = siluf(acc);
  }
  __syncthreads();
  if (d < NEE){
    float acc=0.0f;
    #pragma unroll
    for (int m=0;m<MHH;m++) acc += hl[nn][m]*We2[m*NEE+d];
    atomicAdd(&eng[b*NEE+d], acc);
  } else if (d < NEE+NPP){
    const int p = d-NEE;
    float acc=0.0f;
    #pragma unroll
    for (int m=0;m<MHH;m++) acc += hl[nn][MHH+m]*Wi2[m*NPP+p];
    atomicAdd(&inv[b*NPP+p], acc);
  } else if (d < 7+3*NDD){
    const int idx = d-7;
    const int v = idx/NDD;
    const int dd = idx - v*NDD;
    float acc=0.0f;
    #pragma unroll
    for (int c=0;c<CC;c++) acc += vl[nn][v][c]*Wdp[c*NDD+dd];
    atomicAdd(&dip[(b*3+v)*NDD+dd], acc);
  }
}

// ---------------- final decode ----------------
__global__ __launch_bounds__(64) void final_kernel(
    const float* __restrict__ eng, const float* __restrict__ inv,
    const float* __restrict__ dip, const float* __restrict__ e0g,
    const float* __restrict__ Wd1, const float* __restrict__ bd1,
    const float* __restrict__ Wd2, const float* __restrict__ bd2,
    float* __restrict__ out)
{
  const int g = threadIdx.x;
  if (g >= GG) return;
  float e0 = e0g[g];
  float iv0=inv[g*NPP+0], iv1=inv[g*NPP+1], iv2=inv[g*NPP+2], iv3=inv[g*NPP+3];
  float o0=bd2[0], o1=bd2[1], o2=bd2[2];
  for (int m=0;m<RHH;m++){
    float hm = bd1[m] + iv0*Wd1[0*RHH+m] + iv1*Wd1[1*RHH+m] + iv2*Wd1[2*RHH+m] + iv3*Wd1[3*RHH+m];
    hm = siluf(hm);
    o0 += hm*Wd2[m*NEE+0]; o1 += hm*Wd2[m*NEE+1]; o2 += hm*Wd2[m*NEE+2];
  }
  float* og = out + g*24;
  og[0]=o0+e0; og[1]=o1+e0; og[2]=o2+e0;
  og[3]=eng[g*NEE+0]+e0; og[4]=eng[g*NEE+1]+e0; og[5]=eng[g*NEE+2]+e0;
  for (int dd=0;dd<NDD;dd++)
    for (int v=0;v<3;v++)
      og[6+dd*3+v] = dip[(g*3+v)*NDD+dd];
}

extern "C" void kernel_launch(void* const* d_in, const int* in_sizes, int n_in,
                              void* d_out, int out_size, void* d_ws, size_t ws_size,
                              hipStream_t stream)
{
  const float* pos    = (const float*)d_in[0];
  const float* attrs  = (const float*)d_in[1];
  const float* shifts = (const float*)d_in[2];
  const float* E0v    = (const float*)d_in[3];
  const float* Wemb   = (const float*)d_in[4];
  const float* Wup    = (const float*)d_in[5];
  const float* Wr1    = (const float*)d_in[6];
  const float* Wr2    = (const float*)d_in[7];
  const float* Wr3    = (const float*)d_in[8];
  const float* Wsc    = (const float*)d_in[9];
  const float* Wprod  = (const float*)d_in[10];
  const float* Wc     = (const float*)d_in[11];
  const float* We1    = (const float*)d_in[12];
  const float* We2    = (const float*)d_in[13];
  const float* Wi1    = (const float*)d_in[14];
  const float* Wi2    = (const float*)d_in[15];
  const float* Wdp    = (const float*)d_in[16];
  const float* Wd1    = (const float*)d_in[17];
  const float* bd1    = (const float*)d_in[18];
  const float* Wd2    = (const float*)d_in[19];
  const float* bd2    = (const float*)d_in[20];
  const int*   ei     = (const int*)d_in[21];
  const int*   batch  = (const int*)d_in[22];
  float* out = (float*)d_out;

  float* feats = (float*)d_ws;                 // N*288
  float* agg   = feats + (size_t)NN*SHCC;      // N*288
  float* up    = agg   + (size_t)NN*SHCC;      // N*32
  float* accum = up    + (size_t)NN*CC;        // 1664 floats
  float* e0g = accum;          // 64
  float* eng = accum + 64;     // 64*3
  float* inv = accum + 256;    // 64*4
  float* dip = accum + 512;    // 64*18
  int*   kidx = (int*)(accum + 1664);          // N ints

  hipMemsetAsync(accum, 0, 1664*sizeof(float), stream);
  init_kernel<<<(NN*CC)/256, 256, 0, stream>>>(attrs, E0v, Wemb, batch, kidx, feats, e0g);

  for (int l=0; l<2; ++l){
    up_kernel<<<(NN*CC)/256, 256, 0, stream>>>(feats, Wup + l*CC*CC, up);
    hipMemsetAsync(agg, 0, (size_t)NN*SHCC*sizeof(float), stream);
    edge_kernel<<<512, 256, 0, stream>>>(pos, shifts,
        Wr1 + l*NBB*RHH, Wr2 + l*RHH*RHH, Wr3 + l*RHH*SHCC,
        up, ei, agg);
    node_kernel<<<NN/8, 256, 0, stream>>>(feats, feats, agg, kidx, batch,
        Wsc + l*KK*3*CC*CC, Wprod + l*3*CC*CC, Wc + l*3*KK*CC*CC,
        We1 + l*CC*MHH, We2 + l*MHH*NEE, Wi1 + l*CC*MHH, Wi2 + l*MHH*NPP,
        Wdp + l*CC*NDD,
        eng, inv, dip);
  }
  final_kernel<<<1, 64, 0, stream>>>(eng, inv, dip, e0g, Wd1, bd1, Wd2, bd2, out);
}

// Round 5
// 783.671 us; speedup vs baseline: 1.5420x; 1.2387x over previous
//
#include <hip/hip_runtime.h>
#include <math.h>

#define NN 16000
#define EE 256000
#define GG 64
#define KK 10
#define CC 32
#define NBB 8
#define MHH 16
#define NPP 4
#define NEE 3
#define NDD 6
#define SHH 9
#define RHH 64
#define SHCC (SHH*CC)   // 288

typedef __attribute__((ext_vector_type(8))) short s8b;    // bf16 frag (4 VGPR)
typedef __attribute__((ext_vector_type(4))) float f32x4;  // acc frag

__device__ __forceinline__ float siluf(float x){ return x / (1.0f + __expf(-x)); }
__device__ __forceinline__ short bf16rne(float x){
  unsigned u = __float_as_uint(x);
  unsigned r = u + 0x7FFFu + ((u>>16)&1u);
  return (short)(r>>16);
}

// ---------------- init ----------------
__global__ __launch_bounds__(256) void init_kernel(
    const float* __restrict__ attrs, const float* __restrict__ E0v,
    const float* __restrict__ Wemb, const int* __restrict__ batch,
    int* __restrict__ kidx, float* __restrict__ feats, float* __restrict__ e0g)
{
  int t = blockIdx.x*blockDim.x + threadIdx.x;
  if (t >= NN*CC) return;
  int n = t >> 5, d = t & 31;
  const float* a = attrs + n*KK;
  int k = 0; float best = a[0];
  #pragma unroll
  for (int j=1;j<KK;j++){ float v=a[j]; if (v>best){best=v;k=j;} }
  float* f = feats + n*SHCC;
  f[d] = Wemb[k*CC+d];
  #pragma unroll
  for (int s=1;s<SHH;s++) f[s*CC+d] = 0.0f;
  if (d==0){ kidx[n]=k; atomicAdd(&e0g[batch[n]], E0v[k]); }
}

// ---------------- up ----------------
__global__ __launch_bounds__(256) void up_kernel(
    const float* __restrict__ feats, const float* __restrict__ Wup,
    float* __restrict__ up)
{
  int t = blockIdx.x*blockDim.x + threadIdx.x;
  if (t >= NN*CC) return;
  int n = t >> 5, d = t & 31;
  const float* f = feats + n*SHCC;
  float acc = 0.0f;
  #pragma unroll
  for (int c=0;c<CC;c++) acc += f[c]*Wup[c*CC+d];
  up[t] = acc * 0.0625f;
}

// ---------------- counting sort of edges by dst ----------------
__global__ __launch_bounds__(256) void hist_kernel(
    const int* __restrict__ ei, int* __restrict__ rowptr)
{
  int e = blockIdx.x*256 + threadIdx.x;
  if (e < EE) atomicAdd(&rowptr[ei[EE+e]+1], 1);
}

__global__ __launch_bounds__(1024) void scan_kernel(
    int* __restrict__ rowptr, int* __restrict__ cursor)
{
  __shared__ int part[1024];
  const int t = threadIdx.x;
  const int SEG = 16;           // 1024*16 = 16384 >= NN+1
  const int base = t*SEG;
  int a[SEG];
  int run = 0;
  #pragma unroll
  for (int i=0;i<SEG;i++){
    int idx = base+i;
    int v = (idx <= NN) ? rowptr[idx] : 0;
    run += v; a[i] = run;       // local inclusive prefix
  }
  part[t] = run;
  __syncthreads();
  for (int off=1; off<1024; off<<=1){
    int v = (t>=off) ? part[t-off] : 0;
    __syncthreads();
    part[t] += v;
    __syncthreads();
  }
  int offset = (t>0) ? part[t-1] : 0;
  #pragma unroll
  for (int i=0;i<SEG;i++){
    int idx = base+i;
    if (idx <= NN){
      int val = offset + a[i];
      rowptr[idx] = val;
      if (idx < NN) cursor[idx] = val;
    }
  }
}

__global__ __launch_bounds__(256) void scatter_kernel(
    const int* __restrict__ ei, int* __restrict__ cursor, int* __restrict__ sorted)
{
  int e = blockIdx.x*256 + threadIdx.x;
  if (e < EE){
    int d = ei[EE+e];
    int p = atomicAdd(&cursor[d], 1);
    sorted[p] = e;
  }
}

// ---------------- fused MFMA edge kernel over dst-sorted edges ----------------
// 4 waves/block; wave does 16 sorted edges per tile; per-chunk LDS run-reduce
// turns ~4608 atomics/tile into ~600 with L2-local dst addresses.
__global__ __launch_bounds__(256, 2) void edge_kernel(
    const float* __restrict__ pos, const float* __restrict__ shifts,
    const float* __restrict__ Wr1, const float* __restrict__ Wr2,
    const float* __restrict__ Wr3, const float* __restrict__ up,
    const int* __restrict__ ei, const int* __restrict__ sorted,
    float* __restrict__ agg)
{
  __shared__ alignas(16) short sW3T[SHCC*RHH];  // 36.9 KB bf16 swizzled
  __shared__ alignas(16) short sW2T[RHH*RHH];   // 8 KB bf16 swizzled
  __shared__ alignas(16) float sW1T[RHH*NBB];   // 2 KB f32
  __shared__ alignas(16) float ef_l[4][16*8];
  __shared__ alignas(16) float sh_l[4][16*12];
  __shared__ alignas(16) short h2s_l[4][16*72]; // bf16 h2 transpose, 2.25 KB/wave
  __shared__ alignas(16) float msg_l[4][16*65]; // per-chunk messages, 4.06 KB/wave
  __shared__ int dst_l[4][16];

  for (int i=threadIdx.x; i<RHH*SHCC; i+=256){
    int kk = i/SHCC, o = i - kk*SHCC;
    sW3T[(o*RHH + kk) ^ ((o&7)<<3)] = bf16rne(Wr3[i]);
  }
  for (int i=threadIdx.x; i<RHH*RHH; i+=256){
    int k = i>>6, kk = i&63;
    sW2T[(kk*RHH + k) ^ ((kk&7)<<3)] = bf16rne(Wr2[i]);
  }
  for (int i=threadIdx.x; i<NBB*RHH; i+=256){
    int b = i>>6, k = i&63;
    sW1T[k*NBB + b] = Wr1[i];
  }
  __syncthreads();

  const int lane = threadIdx.x & 63;
  const int el   = lane & 15;
  const int r    = lane >> 4;
  const int wv   = threadIdx.x >> 6;
  float* efw = ef_l[wv];
  float* shw = sh_l[wv];
  short* h2w = h2s_l[wv];
  float* msg = msg_l[wv];
  int*   dstL = dst_l[wv];
  const int wid = blockIdx.x*4 + wv;
  const int nw  = gridDim.x*4;
  const f32x4 zf = {0.f,0.f,0.f,0.f};
  const float PI_ = 3.14159265358979323846f;

  for (int tile = wid; tile < EE/16; tile += nw) {
    const int e0 = tile*16;
    // ---- geometry: lane handles sorted edge e0+el; group r computes bessels r, r+4 ----
    {
      const int e = sorted[e0 + el];
      const int src = ei[e], dst = ei[EE+e];
      if (r==0) dstL[el] = dst;
      float x = pos[src*3+0]-pos[dst*3+0]+shifts[e*3+0];
      float y = pos[src*3+1]-pos[dst*3+1]+shifts[e*3+1];
      float z = pos[src*3+2]-pos[dst*3+2]+shifts[e*3+2];
      float rr = sqrtf(x*x+y*y+z*z+1e-12f);
      float ir = 1.0f/rr;
      x*=ir; y*=ir; z*=ir;
      const float S3=1.7320508075688772f, S5h=1.1180339887498949f;
      const float S15=3.872983346207417f, S15h=1.9364916731037085f;
      if (r==0){ shw[el*12+0]=1.0f;            shw[el*12+1]=S3*x;     shw[el*12+2]=S3*y; }
      else if (r==1){ shw[el*12+3]=S3*z;       shw[el*12+4]=S15*x*y;  shw[el*12+5]=S15*y*z; }
      else if (r==2){ shw[el*12+6]=S5h*(3.0f*z*z-1.0f); shw[el*12+7]=S15*x*z; shw[el*12+8]=S15h*(x*x-y*y); }
      float u = rr*0.2f;
      float u2=u*u, u3=u2*u, u6=u3*u3;
      float env = 1.0f - 28.0f*u6 + 48.0f*u6*u - 21.0f*u6*u2;
      env = (u<1.0f)? env : 0.0f;
      env *= ir * 0.6324555320336759f;
      float n1 = (float)(r+1), n2 = (float)(r+5);
      efw[el*8 + r]     = __sinf(n1*PI_*u)*env;
      efw[el*8 + r + 4] = __sinf(n2*PI_*u)*env;
    }
    // ---- h1 = silu(ef @ W1) in A-frag layout ----
    float h1v[16];
    {
      f32x4 efa = *(const f32x4*)&efw[el*8];
      f32x4 efb = *(const f32x4*)&efw[el*8+4];
      #pragma unroll
      for (int s=0;s<2;s++){
        #pragma unroll
        for (int j=0;j<8;j++){
          int kq = 32*s + 8*r + j;
          f32x4 wa = *(const f32x4*)&sW1T[kq*NBB];
          f32x4 wb = *(const f32x4*)&sW1T[kq*NBB+4];
          float acc = efa[0]*wa[0]+efa[1]*wa[1]+efa[2]*wa[2]+efa[3]*wa[3]
                    + efb[0]*wb[0]+efb[1]*wb[1]+efb[2]*wb[2]+efb[3]*wb[3];
          h1v[s*8+j] = siluf(acc);
        }
      }
    }
    s8b a1s0, a1s1;
    #pragma unroll
    for (int j=0;j<8;j++){ a1s0[j]=bf16rne(h1v[j]); a1s1[j]=bf16rne(h1v[8+j]); }

    // ---- h2 = silu(h1 @ W2) via MFMA ----
    f32x4 aw2[4];
    #pragma unroll
    for (int t=0;t<4;t++){
      int kk = 16*t + el;
      int sw = (kk&7)<<3;
      s8b b0 = *(const s8b*)&sW2T[(kk*RHH + 8*r     ) ^ sw];
      s8b b1 = *(const s8b*)&sW2T[(kk*RHH + 8*r + 32) ^ sw];
      f32x4 acc = __builtin_amdgcn_mfma_f32_16x16x32_bf16(a1s0, b0, zf, 0,0,0);
      aw2[t]    = __builtin_amdgcn_mfma_f32_16x16x32_bf16(a1s1, b1, acc, 0,0,0);
    }
    // transpose h2 (D: row e=4r+reg, col kk=16t+el) via LDS, bf16 direct
    #pragma unroll
    for (int t=0;t<4;t++){
      #pragma unroll
      for (int reg=0;reg<4;reg++)
        h2w[(4*r+reg)*72 + 16*t + el] = bf16rne(siluf(aw2[t][reg]));
    }
    s8b a2s0 = *(const s8b*)&h2w[el*72 + 8*r];
    s8b a2s1 = *(const s8b*)&h2w[el*72 + 32 + 8*r];

    // ---- per-output-edge data (e = 4*r+reg) ----
    float upv[4][2];
    #pragma unroll
    for (int reg=0;reg<4;reg++){
      int ee = sorted[e0 + 4*r + reg];
      int s_ = ei[ee];
      upv[reg][0] = up[s_*CC + el];
      upv[reg][1] = up[s_*CC + 16 + el];
    }
    // ---- Rw = h2 @ W3 via MFMA, chunked LDS run-reduce, one atomic per (run,col) ----
    #pragma unroll
    for (int c=0;c<5;c++){
      const int tBeg = 4*c;
      const int tEnd = (c<4)? (4*c+4) : 18;
      #pragma unroll
      for (int t=tBeg;t<tEnd;t++){
        int o = 16*t + el;
        int sw = (o&7)<<3;
        s8b b0 = *(const s8b*)&sW3T[(o*RHH + 8*r     ) ^ sw];
        s8b b1 = *(const s8b*)&sW3T[(o*RHH + 8*r + 32) ^ sw];
        f32x4 acc = __builtin_amdgcn_mfma_f32_16x16x32_bf16(a2s0, b0, zf, 0,0,0);
        acc       = __builtin_amdgcn_mfma_f32_16x16x32_bf16(a2s1, b1, acc, 0,0,0);
        const int sidx = t>>1, spar = t&1;
        #pragma unroll
        for (int reg=0;reg<4;reg++){
          int e = 4*r + reg;
          float v = acc[reg] * shw[e*12 + sidx] * upv[reg][spar];
          msg[e*65 + 16*(t-tBeg) + el] = v;
        }
      }
      // run-reduce over sorted dst within the tile
      const int colIdx = (c<4) ? lane : (lane & 31);
      const bool active = (c<4) || (lane < 32);
      const int obase = 64*c;
      int i = 0;
      while (i < 16){
        int d = dstL[i];
        float a = msg[i*65 + colIdx];
        int j = i+1;
        while (j < 16 && dstL[j]==d){ a += msg[j*65 + colIdx]; j++; }
        if (active) atomicAdd(agg + (size_t)d*SHCC + obase + colIdx, a);
        i = j;
      }
    }
  }
}

// ---------------- node update + readouts ----------------
__global__ __launch_bounds__(256) void node_kernel(
    const float* __restrict__ feats, float* __restrict__ fout,
    const float* __restrict__ agg,
    const int* __restrict__ kidx, const int* __restrict__ batch,
    const float* __restrict__ Wsc, const float* __restrict__ Wprod,
    const float* __restrict__ WcL,
    const float* __restrict__ We1, const float* __restrict__ We2,
    const float* __restrict__ Wi1, const float* __restrict__ Wi2,
    const float* __restrict__ Wdp,
    float* __restrict__ eng, float* __restrict__ inv, float* __restrict__ dip)
{
  __shared__ float s0l[8][CC];
  __shared__ float sul[8][CC];
  __shared__ float vl[8][3][CC];
  __shared__ float hl[8][CC];
  const int t = threadIdx.x;
  const int nn = t >> 5;
  const int d = t & 31;
  const int n = blockIdx.x*8 + nn;
  const int k = kidx[n];
  const int b = batch[n];
  const float* fin = feats + n*SHCC;
  const float* ag = agg + n*SHCC;
  float nw[SHH];
  const int LV[SHH] = {0,1,1,1,2,2,2,2,2};
  #pragma unroll
  for (int s=0;s<SHH;s++){
    const int lv = LV[s];
    const float* wp  = Wprod + lv*CC*CC + d;
    const float* wsc = Wsc + (k*3+lv)*CC*CC + d;
    float acc = 0.0f;
    #pragma unroll
    for (int c=0;c<CC;c++)
      acc += ag[s*CC+c]*wp[c*CC] + fin[s*CC+c]*wsc[c*CC];
    nw[s] = acc;
  }
  s0l[nn][d] = nw[0];
  vl[nn][0][d] = nw[1]; vl[nn][1][d] = nw[2]; vl[nn][2][d] = nw[3];
  __syncthreads();
  float corr = 0.0f;
  {
    const float* wc0 = WcL + (0*KK+k)*CC*CC + d;
    const float* wc1 = WcL + (1*KK+k)*CC*CC + d;
    const float* wc2 = WcL + (2*KK+k)*CC*CC + d;
    #pragma unroll
    for (int c=0;c<CC;c++){
      float s0 = s0l[nn][c];
      float s2 = s0*s0;
      corr += s0*wc0[c*CC] + s2*wc1[c*CC] + s2*s0*wc2[c*CC];
    }
  }
  float su = nw[0] + corr;
  sul[nn][d] = su;
  float* fo = fout + n*SHCC;
  fo[d] = su;
  #pragma unroll
  for (int s=1;s<SHH;s++) fo[s*CC+d] = nw[s];
  __syncthreads();
  {
    const int m = d & 15;
    const float* W = (d < MHH) ? We1 : Wi1;
    float acc = 0.0f;
    #pragma unroll
    for (int c=0;c<CC;c++) acc += sul[nn][c]*W[c*MHH+m];
    hl[nn][d] = siluf(acc);
  }
  __syncthreads();
  if (d < NEE){
    float acc=0.0f;
    #pragma unroll
    for (int m=0;m<MHH;m++) acc += hl[nn][m]*We2[m*NEE+d];
    atomicAdd(&eng[b*NEE+d], acc);
  } else if (d < NEE+NPP){
    const int p = d-NEE;
    float acc=0.0f;
    #pragma unroll
    for (int m=0;m<MHH;m++) acc += hl[nn][MHH+m]*Wi2[m*NPP+p];
    atomicAdd(&inv[b*NPP+p], acc);
  } else if (d < 7+3*NDD){
    const int idx = d-7;
    const int v = idx/NDD;
    const int dd = idx - v*NDD;
    float acc=0.0f;
    #pragma unroll
    for (int c=0;c<CC;c++) acc += vl[nn][v][c]*Wdp[c*NDD+dd];
    atomicAdd(&dip[(b*3+v)*NDD+dd], acc);
  }
}

// ---------------- final decode ----------------
__global__ __launch_bounds__(64) void final_kernel(
    const float* __restrict__ eng, const float* __restrict__ inv,
    const float* __restrict__ dip, const float* __restrict__ e0g,
    const float* __restrict__ Wd1, const float* __restrict__ bd1,
    const float* __restrict__ Wd2, const float* __restrict__ bd2,
    float* __restrict__ out)
{
  const int g = threadIdx.x;
  if (g >= GG) return;
  float e0 = e0g[g];
  float iv0=inv[g*NPP+0], iv1=inv[g*NPP+1], iv2=inv[g*NPP+2], iv3=inv[g*NPP+3];
  float o0=bd2[0], o1=bd2[1], o2=bd2[2];
  for (int m=0;m<RHH;m++){
    float hm = bd1[m] + iv0*Wd1[0*RHH+m] + iv1*Wd1[1*RHH+m] + iv2*Wd1[2*RHH+m] + iv3*Wd1[3*RHH+m];
    hm = siluf(hm);
    o0 += hm*Wd2[m*NEE+0]; o1 += hm*Wd2[m*NEE+1]; o2 += hm*Wd2[m*NEE+2];
  }
  float* og = out + g*24;
  og[0]=o0+e0; og[1]=o1+e0; og[2]=o2+e0;
  og[3]=eng[g*NEE+0]+e0; og[4]=eng[g*NEE+1]+e0; og[5]=eng[g*NEE+2]+e0;
  for (int dd=0;dd<NDD;dd++)
    for (int v=0;v<3;v++)
      og[6+dd*3+v] = dip[(g*3+v)*NDD+dd];
}

extern "C" void kernel_launch(void* const* d_in, const int* in_sizes, int n_in,
                              void* d_out, int out_size, void* d_ws, size_t ws_size,
                              hipStream_t stream)
{
  const float* pos    = (const float*)d_in[0];
  const float* attrs  = (const float*)d_in[1];
  const float* shifts = (const float*)d_in[2];
  const float* E0v    = (const float*)d_in[3];
  const float* Wemb   = (const float*)d_in[4];
  const float* Wup    = (const float*)d_in[5];
  const float* Wr1    = (const float*)d_in[6];
  const float* Wr2    = (const float*)d_in[7];
  const float* Wr3    = (const float*)d_in[8];
  const float* Wsc    = (const float*)d_in[9];
  const float* Wprod  = (const float*)d_in[10];
  const float* Wc     = (const float*)d_in[11];
  const float* We1    = (const float*)d_in[12];
  const float* We2    = (const float*)d_in[13];
  const float* Wi1    = (const float*)d_in[14];
  const float* Wi2    = (const float*)d_in[15];
  const float* Wdp    = (const float*)d_in[16];
  const float* Wd1    = (const float*)d_in[17];
  const float* bd1    = (const float*)d_in[18];
  const float* Wd2    = (const float*)d_in[19];
  const float* bd2    = (const float*)d_in[20];
  const int*   ei     = (const int*)d_in[21];
  const int*   batch  = (const int*)d_in[22];
  float* out = (float*)d_out;

  float* feats = (float*)d_ws;                 // N*288
  float* agg   = feats + (size_t)NN*SHCC;      // N*288
  float* up    = agg   + (size_t)NN*SHCC;      // N*32
  float* accum = up    + (size_t)NN*CC;        // 1664 floats
  float* e0g = accum;          // 64
  float* eng = accum + 64;     // 64*3
  float* inv = accum + 256;    // 64*4
  float* dip = accum + 512;    // 64*18
  int*   kidx   = (int*)(accum + 1664);        // N ints
  int*   rowptr = kidx + NN;                   // NN+1 ints
  int*   cursor = rowptr + NN + 1;             // NN ints
  int*   sorted = cursor + NN;                 // EE ints

  hipMemsetAsync(accum, 0, 1664*sizeof(float), stream);
  hipMemsetAsync(rowptr, 0, (NN+1)*sizeof(int), stream);
  init_kernel<<<(NN*CC)/256, 256, 0, stream>>>(attrs, E0v, Wemb, batch, kidx, feats, e0g);
  hist_kernel<<<EE/256, 256, 0, stream>>>(ei, rowptr);
  scan_kernel<<<1, 1024, 0, stream>>>(rowptr, cursor);
  scatter_kernel<<<EE/256, 256, 0, stream>>>(ei, cursor, sorted);

  for (int l=0; l<2; ++l){
    up_kernel<<<(NN*CC)/256, 256, 0, stream>>>(feats, Wup + l*CC*CC, up);
    hipMemsetAsync(agg, 0, (size_t)NN*SHCC*sizeof(float), stream);
    edge_kernel<<<512, 256, 0, stream>>>(pos, shifts,
        Wr1 + l*NBB*RHH, Wr2 + l*RHH*RHH, Wr3 + l*RHH*SHCC,
        up, ei, sorted, agg);
    node_kernel<<<NN/8, 256, 0, stream>>>(feats, feats, agg, kidx, batch,
        Wsc + l*KK*3*CC*CC, Wprod + l*3*CC*CC, Wc + l*3*KK*CC*CC,
        We1 + l*CC*MHH, We2 + l*MHH*NEE, Wi1 + l*CC*MHH, Wi2 + l*MHH*NPP,
        Wdp + l*CC*NDD,
        eng, inv, dip);
  }
  final_kernel<<<1, 64, 0, stream>>>(eng, inv, dip, e0g, Wd1, bd1, Wd2, bd2, out);
}

// Round 6
// 767.302 us; speedup vs baseline: 1.5749x; 1.0213x over previous
//
#include <hip/hip_runtime.h>
#include <math.h>

#define NN 16000
#define EE 256000
#define GG 64
#define KK 10
#define CC 32
#define NBB 8
#define MHH 16
#define NPP 4
#define NEE 3
#define NDD 6
#define SHH 9
#define RHH 64
#define SHCC (SHH*CC)   // 288

typedef __attribute__((ext_vector_type(8))) short s8b;    // bf16 frag (4 VGPR)
typedef __attribute__((ext_vector_type(4))) float f32x4;  // acc frag

__device__ __forceinline__ float siluf(float x){ return x / (1.0f + __expf(-x)); }
__device__ __forceinline__ short bf16rne(float x){
  unsigned u = __float_as_uint(x);
  unsigned r = u + 0x7FFFu + ((u>>16)&1u);
  return (short)(r>>16);
}

// ---------------- init: kidx, feats0, e0, up(l=0) ----------------
__global__ __launch_bounds__(256) void init_kernel(
    const float* __restrict__ attrs, const float* __restrict__ E0v,
    const float* __restrict__ Wemb, const float* __restrict__ Wup0,
    const int* __restrict__ batch,
    int* __restrict__ kidx, float* __restrict__ feats, float* __restrict__ e0g,
    float* __restrict__ up)
{
  int t = blockIdx.x*blockDim.x + threadIdx.x;
  if (t >= NN*CC) return;
  int n = t >> 5, d = t & 31;
  const float* a = attrs + n*KK;
  int k = 0; float best = a[0];
  #pragma unroll
  for (int j=1;j<KK;j++){ float v=a[j]; if (v>best){best=v;k=j;} }
  float* f = feats + n*SHCC;
  f[d] = Wemb[k*CC+d];
  #pragma unroll
  for (int s=1;s<SHH;s++) f[s*CC+d] = 0.0f;
  // up(l=0) = Wemb[k,:] @ Wup0, folded /AVG_NBR
  float accu = 0.0f;
  #pragma unroll
  for (int c=0;c<CC;c++) accu += Wemb[k*CC+c]*Wup0[c*CC+d];
  up[n*CC+d] = accu * 0.0625f;
  if (d==0){ kidx[n]=k; atomicAdd(&e0g[batch[n]], E0v[k]); }
}

// ---------------- counting sort of edges by dst ----------------
__global__ __launch_bounds__(256) void hist_kernel(
    const int* __restrict__ ei, int* __restrict__ rowptr)
{
  int e = blockIdx.x*256 + threadIdx.x;
  if (e < EE) atomicAdd(&rowptr[ei[EE+e]+1], 1);
}

__global__ __launch_bounds__(1024) void scan_kernel(
    int* __restrict__ rowptr, int* __restrict__ cursor)
{
  __shared__ int part[1024];
  const int t = threadIdx.x;
  const int SEG = 16;
  const int base = t*SEG;
  int a[SEG];
  int run = 0;
  #pragma unroll
  for (int i=0;i<SEG;i++){
    int idx = base+i;
    int v = (idx <= NN) ? rowptr[idx] : 0;
    run += v; a[i] = run;
  }
  part[t] = run;
  __syncthreads();
  for (int off=1; off<1024; off<<=1){
    int v = (t>=off) ? part[t-off] : 0;
    __syncthreads();
    part[t] += v;
    __syncthreads();
  }
  int offset = (t>0) ? part[t-1] : 0;
  #pragma unroll
  for (int i=0;i<SEG;i++){
    int idx = base+i;
    if (idx <= NN){
      int val = offset + a[i];
      rowptr[idx] = val;
      if (idx < NN) cursor[idx] = val;
    }
  }
}

__global__ __launch_bounds__(256) void scatter_kernel(
    const int* __restrict__ ei, int* __restrict__ cursor, int* __restrict__ sorted)
{
  int e = blockIdx.x*256 + threadIdx.x;
  if (e < EE){
    int d = ei[EE+e];
    int p = atomicAdd(&cursor[d], 1);
    sorted[p] = e;
  }
}

// ---------------- fused MFMA edge kernel: block-cooperative 64-edge windows ----------------
// 4 waves process one window of 64 dst-sorted edges; shared msg[64][65];
// run boundaries via ballot once per window; reduce 4-way parallel over runs.
__global__ __launch_bounds__(256, 2) void edge_kernel(
    const float* __restrict__ pos, const float* __restrict__ shifts,
    const float* __restrict__ Wr1, const float* __restrict__ Wr2,
    const float* __restrict__ Wr3, const float* __restrict__ up,
    const int* __restrict__ ei, const int* __restrict__ sorted,
    float* __restrict__ agg)
{
  __shared__ alignas(16) short sW3T[SHCC*RHH];      // 36864 B
  __shared__ alignas(16) short sW2T[RHH*RHH];       // 8192 B
  __shared__ alignas(16) float sW1T[RHH*NBB];       // 2048 B
  __shared__ alignas(16) char  uni[64*65*4];        // 16640 B: msg | {ef, h2s}
  __shared__ alignas(16) float sh_l[4][16*12];      // 3072 B
  __shared__ int dst_l[64];                         // 256 B

  for (int i=threadIdx.x; i<RHH*SHCC; i+=256){
    int kk = i/SHCC, o = i - kk*SHCC;
    sW3T[(o*RHH + kk) ^ ((o&7)<<3)] = bf16rne(Wr3[i]);
  }
  for (int i=threadIdx.x; i<RHH*RHH; i+=256){
    int k = i>>6, kk = i&63;
    sW2T[(kk*RHH + k) ^ ((kk&7)<<3)] = bf16rne(Wr2[i]);
  }
  for (int i=threadIdx.x; i<NBB*RHH; i+=256){
    int b = i>>6, k = i&63;
    sW1T[k*NBB + b] = Wr1[i];
  }
  __syncthreads();

  const int tid  = threadIdx.x;
  const int lane = tid & 63;
  const int el   = lane & 15;
  const int r    = lane >> 4;
  const int wv   = tid >> 6;
  float* msg = (float*)uni;                         // [64][65]
  float* efw = (float*)(uni + wv*512);              // 16*8 floats per wave
  short* h2w = (short*)(uni + 2048 + wv*2304);      // 16*72 shorts per wave
  float* shw = sh_l[wv];
  const f32x4 zf = {0.f,0.f,0.f,0.f};
  const float PI_ = 3.14159265358979323846f;

  for (int w = blockIdx.x; w < EE/64; w += gridDim.x) {
    const int e0 = w*64 + wv*16;
    // ---- phase A (wave-private): geometry, h1, h2, frags ----
    {
      const int e = sorted[e0 + el];
      const int src = ei[e], dst = ei[EE+e];
      if (r==0) dst_l[wv*16+el] = dst;
      float x = pos[src*3+0]-pos[dst*3+0]+shifts[e*3+0];
      float y = pos[src*3+1]-pos[dst*3+1]+shifts[e*3+1];
      float z = pos[src*3+2]-pos[dst*3+2]+shifts[e*3+2];
      float rr = sqrtf(x*x+y*y+z*z+1e-12f);
      float ir = 1.0f/rr;
      x*=ir; y*=ir; z*=ir;
      const float S3=1.7320508075688772f, S5h=1.1180339887498949f;
      const float S15=3.872983346207417f, S15h=1.9364916731037085f;
      if (r==0){ shw[el*12+0]=1.0f;            shw[el*12+1]=S3*x;     shw[el*12+2]=S3*y; }
      else if (r==1){ shw[el*12+3]=S3*z;       shw[el*12+4]=S15*x*y;  shw[el*12+5]=S15*y*z; }
      else if (r==2){ shw[el*12+6]=S5h*(3.0f*z*z-1.0f); shw[el*12+7]=S15*x*z; shw[el*12+8]=S15h*(x*x-y*y); }
      float u = rr*0.2f;
      float u2=u*u, u3=u2*u, u6=u3*u3;
      float env = 1.0f - 28.0f*u6 + 48.0f*u6*u - 21.0f*u6*u2;
      env = (u<1.0f)? env : 0.0f;
      env *= ir * 0.6324555320336759f;
      float n1 = (float)(r+1), n2 = (float)(r+5);
      efw[el*8 + r]     = __sinf(n1*PI_*u)*env;
      efw[el*8 + r + 4] = __sinf(n2*PI_*u)*env;
    }
    float h1v[16];
    {
      f32x4 efa = *(const f32x4*)&efw[el*8];
      f32x4 efb = *(const f32x4*)&efw[el*8+4];
      #pragma unroll
      for (int s=0;s<2;s++){
        #pragma unroll
        for (int j=0;j<8;j++){
          int kq = 32*s + 8*r + j;
          f32x4 wa = *(const f32x4*)&sW1T[kq*NBB];
          f32x4 wb = *(const f32x4*)&sW1T[kq*NBB+4];
          float acc = efa[0]*wa[0]+efa[1]*wa[1]+efa[2]*wa[2]+efa[3]*wa[3]
                    + efb[0]*wb[0]+efb[1]*wb[1]+efb[2]*wb[2]+efb[3]*wb[3];
          h1v[s*8+j] = siluf(acc);
        }
      }
    }
    s8b a1s0, a1s1;
    #pragma unroll
    for (int j=0;j<8;j++){ a1s0[j]=bf16rne(h1v[j]); a1s1[j]=bf16rne(h1v[8+j]); }

    f32x4 aw2[4];
    #pragma unroll
    for (int t=0;t<4;t++){
      int kk = 16*t + el;
      int sw = (kk&7)<<3;
      s8b b0 = *(const s8b*)&sW2T[(kk*RHH + 8*r     ) ^ sw];
      s8b b1 = *(const s8b*)&sW2T[(kk*RHH + 8*r + 32) ^ sw];
      f32x4 acc = __builtin_amdgcn_mfma_f32_16x16x32_bf16(a1s0, b0, zf, 0,0,0);
      aw2[t]    = __builtin_amdgcn_mfma_f32_16x16x32_bf16(a1s1, b1, acc, 0,0,0);
    }
    #pragma unroll
    for (int t=0;t<4;t++){
      #pragma unroll
      for (int reg=0;reg<4;reg++)
        h2w[(4*r+reg)*72 + 16*t + el] = bf16rne(siluf(aw2[t][reg]));
    }
    s8b a2s0 = *(const s8b*)&h2w[el*72 + 8*r];
    s8b a2s1 = *(const s8b*)&h2w[el*72 + 32 + 8*r];

    float upv[4][2];
    #pragma unroll
    for (int reg=0;reg<4;reg++){
      int ee = sorted[e0 + 4*r + reg];
      int s_ = ei[ee];
      upv[reg][0] = up[s_*CC + el];
      upv[reg][1] = up[s_*CC + 16 + el];
    }
    __syncthreads();   // phase A done; ef/h2 dead; dst_l complete

    // run mask (identical in all waves)
    unsigned long long runmask;
    {
      bool flag = (lane==0) || (dst_l[lane] != dst_l[lane-1]);
      runmask = __ballot(flag);
    }

    // ---- chunked W3 MFMA + block run-reduce ----
    #pragma unroll
    for (int c=0;c<5;c++){
      const int tBeg = 4*c;
      const int tEnd = (c<4)? (tBeg+4) : 18;
      for (int t=tBeg;t<tEnd;t++){
        int o = 16*t + el;
        int sw = (o&7)<<3;
        s8b b0 = *(const s8b*)&sW3T[(o*RHH + 8*r     ) ^ sw];
        s8b b1 = *(const s8b*)&sW3T[(o*RHH + 8*r + 32) ^ sw];
        f32x4 acc = __builtin_amdgcn_mfma_f32_16x16x32_bf16(a2s0, b0, zf, 0,0,0);
        acc       = __builtin_amdgcn_mfma_f32_16x16x32_bf16(a2s1, b1, acc, 0,0,0);
        const int sidx = t>>1, spar = t&1;
        #pragma unroll
        for (int reg=0;reg<4;reg++){
          float v = acc[reg] * shw[(4*r+reg)*12 + sidx] * upv[reg][spar];
          msg[(wv*16 + 4*r + reg)*65 + 16*(t-tBeg) + el] = v;
        }
      }
      __syncthreads();
      {
        const int col = (c<4) ? (tid & 63) : (tid & 31);
        const bool act = (c<4) || ((tid & 63) < 32);
        const int q = tid >> 6;
        const int obase = 64*c;
        if (act){
          unsigned long long m = runmask;
          int j = 0;
          while (m){
            int s = __builtin_ctzll(m);
            m &= (m-1);
            int en = m ? __builtin_ctzll(m) : 64;
            if ((j & 3) == q){
              float a = 0.0f;
              for (int i=s;i<en;i++) a += msg[i*65 + col];
              atomicAdd(agg + (size_t)dst_l[s]*SHCC + obase + col, a);
            }
            j++;
          }
        }
      }
      __syncthreads();
    }
  }
}

// ---------------- node update + readouts + up(l+1) ----------------
__global__ __launch_bounds__(256) void node_kernel(
    const float* __restrict__ feats, float* __restrict__ fout,
    const float* __restrict__ agg,
    const int* __restrict__ kidx, const int* __restrict__ batch,
    const float* __restrict__ Wsc, const float* __restrict__ Wprod,
    const float* __restrict__ WcL,
    const float* __restrict__ We1, const float* __restrict__ We2,
    const float* __restrict__ Wi1, const float* __restrict__ Wi2,
    const float* __restrict__ Wdp, const float* __restrict__ Wup1,
    float* __restrict__ up,
    float* __restrict__ eng, float* __restrict__ inv, float* __restrict__ dip)
{
  __shared__ float s0l[8][CC];
  __shared__ float sul[8][CC];
  __shared__ float vl[8][3][CC];
  __shared__ float hl[8][CC];
  const int t = threadIdx.x;
  const int nn = t >> 5;
  const int d = t & 31;
  const int n = blockIdx.x*8 + nn;
  const int k = kidx[n];
  const int b = batch[n];
  const float* fin = feats + n*SHCC;
  const float* ag = agg + n*SHCC;
  float nw[SHH];
  const int LV[SHH] = {0,1,1,1,2,2,2,2,2};
  #pragma unroll
  for (int s=0;s<SHH;s++){
    const int lv = LV[s];
    const float* wp  = Wprod + lv*CC*CC + d;
    const float* wsc = Wsc + (k*3+lv)*CC*CC + d;
    float acc = 0.0f;
    #pragma unroll
    for (int c=0;c<CC;c++)
      acc += ag[s*CC+c]*wp[c*CC] + fin[s*CC+c]*wsc[c*CC];
    nw[s] = acc;
  }
  s0l[nn][d] = nw[0];
  vl[nn][0][d] = nw[1]; vl[nn][1][d] = nw[2]; vl[nn][2][d] = nw[3];
  __syncthreads();
  float corr = 0.0f;
  {
    const float* wc0 = WcL + (0*KK+k)*CC*CC + d;
    const float* wc1 = WcL + (1*KK+k)*CC*CC + d;
    const float* wc2 = WcL + (2*KK+k)*CC*CC + d;
    #pragma unroll
    for (int c=0;c<CC;c++){
      float s0 = s0l[nn][c];
      float s2 = s0*s0;
      corr += s0*wc0[c*CC] + s2*wc1[c*CC] + s2*s0*wc2[c*CC];
    }
  }
  float su = nw[0] + corr;
  sul[nn][d] = su;
  float* fo = fout + n*SHCC;
  fo[d] = su;
  #pragma unroll
  for (int s=1;s<SHH;s++) fo[s*CC+d] = nw[s];
  __syncthreads();
  {
    const int m = d & 15;
    const float* W = (d < MHH) ? We1 : Wi1;
    float acc = 0.0f;
    #pragma unroll
    for (int c=0;c<CC;c++) acc += sul[nn][c]*W[c*MHH+m];
    hl[nn][d] = siluf(acc);
  }
  // up for next layer (folded /AVG_NBR)
  {
    float acc = 0.0f;
    #pragma unroll
    for (int c=0;c<CC;c++) acc += sul[nn][c]*Wup1[c*CC+d];
    up[n*CC+d] = acc * 0.0625f;
  }
  __syncthreads();
  if (d < NEE){
    float acc=0.0f;
    #pragma unroll
    for (int m=0;m<MHH;m++) acc += hl[nn][m]*We2[m*NEE+d];
    atomicAdd(&eng[b*NEE+d], acc);
  } else if (d < NEE+NPP){
    const int p = d-NEE;
    float acc=0.0f;
    #pragma unroll
    for (int m=0;m<MHH;m++) acc += hl[nn][MHH+m]*Wi2[m*NPP+p];
    atomicAdd(&inv[b*NPP+p], acc);
  } else if (d < 7+3*NDD){
    const int idx = d-7;
    const int v = idx/NDD;
    const int dd = idx - v*NDD;
    float acc=0.0f;
    #pragma unroll
    for (int c=0;c<CC;c++) acc += vl[nn][v][c]*Wdp[c*NDD+dd];
    atomicAdd(&dip[(b*3+v)*NDD+dd], acc);
  }
}

// ---------------- final decode ----------------
__global__ __launch_bounds__(64) void final_kernel(
    const float* __restrict__ eng, const float* __restrict__ inv,
    const float* __restrict__ dip, const float* __restrict__ e0g,
    const float* __restrict__ Wd1, const float* __restrict__ bd1,
    const float* __restrict__ Wd2, const float* __restrict__ bd2,
    float* __restrict__ out)
{
  const int g = threadIdx.x;
  if (g >= GG) return;
  float e0 = e0g[g];
  float iv0=inv[g*NPP+0], iv1=inv[g*NPP+1], iv2=inv[g*NPP+2], iv3=inv[g*NPP+3];
  float o0=bd2[0], o1=bd2[1], o2=bd2[2];
  for (int m=0;m<RHH;m++){
    float hm = bd1[m] + iv0*Wd1[0*RHH+m] + iv1*Wd1[1*RHH+m] + iv2*Wd1[2*RHH+m] + iv3*Wd1[3*RHH+m];
    hm = siluf(hm);
    o0 += hm*Wd2[m*NEE+0]; o1 += hm*Wd2[m*NEE+1]; o2 += hm*Wd2[m*NEE+2];
  }
  float* og = out + g*24;
  og[0]=o0+e0; og[1]=o1+e0; og[2]=o2+e0;
  og[3]=eng[g*NEE+0]+e0; og[4]=eng[g*NEE+1]+e0; og[5]=eng[g*NEE+2]+e0;
  for (int dd=0;dd<NDD;dd++)
    for (int v=0;v<3;v++)
      og[6+dd*3+v] = dip[(g*3+v)*NDD+dd];
}

extern "C" void kernel_launch(void* const* d_in, const int* in_sizes, int n_in,
                              void* d_out, int out_size, void* d_ws, size_t ws_size,
                              hipStream_t stream)
{
  const float* pos    = (const float*)d_in[0];
  const float* attrs  = (const float*)d_in[1];
  const float* shifts = (const float*)d_in[2];
  const float* E0v    = (const float*)d_in[3];
  const float* Wemb   = (const float*)d_in[4];
  const float* Wup    = (const float*)d_in[5];
  const float* Wr1    = (const float*)d_in[6];
  const float* Wr2    = (const float*)d_in[7];
  const float* Wr3    = (const float*)d_in[8];
  const float* Wsc    = (const float*)d_in[9];
  const float* Wprod  = (const float*)d_in[10];
  const float* Wc     = (const float*)d_in[11];
  const float* We1    = (const float*)d_in[12];
  const float* We2    = (const float*)d_in[13];
  const float* Wi1    = (const float*)d_in[14];
  const float* Wi2    = (const float*)d_in[15];
  const float* Wdp    = (const float*)d_in[16];
  const float* Wd1    = (const float*)d_in[17];
  const float* bd1    = (const float*)d_in[18];
  const float* Wd2    = (const float*)d_in[19];
  const float* bd2    = (const float*)d_in[20];
  const int*   ei     = (const int*)d_in[21];
  const int*   batch  = (const int*)d_in[22];
  float* out = (float*)d_out;

  float* feats = (float*)d_ws;                 // N*288
  float* agg   = feats + (size_t)NN*SHCC;      // N*288
  float* up    = agg   + (size_t)NN*SHCC;      // N*32
  float* accum = up    + (size_t)NN*CC;        // 1664 floats
  float* e0g = accum;          // 64
  float* eng = accum + 64;     // 64*3
  float* inv = accum + 256;    // 64*4
  float* dip = accum + 512;    // 64*18
  int*   kidx   = (int*)(accum + 1664);        // N ints
  int*   rowptr = kidx + NN;                   // NN+1 ints
  int*   cursor = rowptr + NN + 1;             // NN ints
  int*   sorted = cursor + NN;                 // EE ints

  hipMemsetAsync(accum, 0, 1664*sizeof(float), stream);
  hipMemsetAsync(rowptr, 0, (NN+1)*sizeof(int), stream);
  init_kernel<<<(NN*CC)/256, 256, 0, stream>>>(attrs, E0v, Wemb, Wup, batch, kidx, feats, e0g, up);
  hist_kernel<<<EE/256, 256, 0, stream>>>(ei, rowptr);
  scan_kernel<<<1, 1024, 0, stream>>>(rowptr, cursor);
  scatter_kernel<<<EE/256, 256, 0, stream>>>(ei, cursor, sorted);

  for (int l=0; l<2; ++l){
    hipMemsetAsync(agg, 0, (size_t)NN*SHCC*sizeof(float), stream);
    edge_kernel<<<512, 256, 0, stream>>>(pos, shifts,
        Wr1 + l*NBB*RHH, Wr2 + l*RHH*RHH, Wr3 + l*RHH*SHCC,
        up, ei, sorted, agg);
    node_kernel<<<NN/8, 256, 0, stream>>>(feats, feats, agg, kidx, batch,
        Wsc + l*KK*3*CC*CC, Wprod + l*3*CC*CC, Wc + l*3*KK*CC*CC,
        We1 + l*CC*MHH, We2 + l*MHH*NEE, Wi1 + l*CC*MHH, Wi2 + l*MHH*NPP,
        Wdp + l*CC*NDD, Wup + 1*CC*CC, up,
        eng, inv, dip);
  }
  final_kernel<<<1, 64, 0, stream>>>(eng, inv, dip, e0g, Wd1, bd1, Wd2, bd2, out);
}